// Round 1
// baseline (501.899 us; speedup 1.0000x reference)
//
#include <hip/hip_runtime.h>
#include <cstdint>
#include <cstddef>

#define BB 16
#define NN 1024
#define DD 128
#define RR (BB*NN)
#define MAXDEG 256
#define NHOP 4

typedef unsigned long long u64;
typedef unsigned short u16;
typedef unsigned int u32;

// ---------------- K0: adjacency row -> bitmask + degree ----------------
// one wave per row; deterministic (k-ascending) structure
__global__ void k_compact(const float* __restrict__ adj,
                          u64* __restrict__ bm, u32* __restrict__ deg) {
  int row = blockIdx.x;
  int l = threadIdx.x;                       // 0..63
  const float* arow = adj + (size_t)row * NN;
  int base = 0;
  for (int r = 0; r < 16; ++r) {
    float v = arow[r * 64 + l];
    u64 m = __ballot(v > 0.0f);
    if (l == 0) bm[row * 16 + r] = m;
    base += __popcll(m);
  }
  if (l == 0) deg[row] = (u32)base;
}

// ---------------- transpose A (128x128) -> At[c][k] = A[k][c] ----------------
__global__ void k_transpose(const float* __restrict__ A, float* __restrict__ At) {
  int e = blockIdx.x * 256 + threadIdx.x;    // 0..16383
  int r = e >> 7, c = e & 127;
  At[c * 128 + r] = A[r * 128 + c];
}

// ---------------- generic C[M x 128] = A[M x 128] * B[128 x 128]^T (+bias) ----------------
// B given row-major as [out_col][kk]. 64 rows per block, 8x4 per thread.
#define GB_BK 64
__global__ __launch_bounds__(256, 3)
void k_gemm_bt(const float* __restrict__ Am, const float* __restrict__ Bm,
               const float* __restrict__ bias, float* __restrict__ Cm) {
  __shared__ float a_lds[64][GB_BK + 1];
  __shared__ float b_lds[128][GB_BK + 1];
  int t = threadIdx.x;
  int tj = t >> 5;        // 0..7
  int tk = t & 31;        // 0..31
  int rowbase = blockIdx.x * 64;
  float acc[8][4];
#pragma unroll
  for (int i = 0; i < 8; i++)
#pragma unroll
    for (int j = 0; j < 4; j++) acc[i][j] = 0.f;

  for (int kc = 0; kc < 128; kc += GB_BK) {
    // A tile: 64 x 64  (1024 float4)
#pragma unroll
    for (int i = 0; i < 4; ++i) {
      int e = t + i * 256;
      int r = e >> 4, kq = e & 15;
      float4 v = *(const float4*)(Am + (size_t)(rowbase + r) * DD + kc + kq * 4);
      a_lds[r][kq * 4 + 0] = v.x; a_lds[r][kq * 4 + 1] = v.y;
      a_lds[r][kq * 4 + 2] = v.z; a_lds[r][kq * 4 + 3] = v.w;
    }
    // B tile: 128 x 64 (2048 float4)
#pragma unroll
    for (int i = 0; i < 8; ++i) {
      int e = t + i * 256;
      int r = e >> 4, kq = e & 15;
      float4 v = *(const float4*)(Bm + (size_t)r * DD + kc + kq * 4);
      b_lds[r][kq * 4 + 0] = v.x; b_lds[r][kq * 4 + 1] = v.y;
      b_lds[r][kq * 4 + 2] = v.z; b_lds[r][kq * 4 + 3] = v.w;
    }
    __syncthreads();
#pragma unroll
    for (int kk = 0; kk < GB_BK; ++kk) {
      float av[8], bv[4];
#pragma unroll
      for (int i = 0; i < 8; i++) av[i] = a_lds[tj + 8 * i][kk];
#pragma unroll
      for (int j = 0; j < 4; j++) bv[j] = b_lds[tk + 32 * j][kk];
#pragma unroll
      for (int i = 0; i < 8; i++)
#pragma unroll
        for (int j = 0; j < 4; j++)
          acc[i][j] = fmaf(av[i], bv[j], acc[i][j]);
    }
    __syncthreads();
  }
#pragma unroll
  for (int i = 0; i < 8; i++) {
    int gr = rowbase + tj + 8 * i;
#pragma unroll
    for (int j = 0; j < 4; j++) {
      int c = tk + 32 * j;
      float v = acc[i][j];
      if (bias) v += bias[c];
      Cm[(size_t)gr * DD + c] = v;
    }
  }
}

// ---------------- e' kernel: symmetric bilinear scores, masked ----------------
// per batch, J<=K 128x128 tile pairs; thread computes e_sym directly; writes tile + mirror.
#define EB_BK 32
__global__ __launch_bounds__(256, 2)
void k_e(const float* __restrict__ h, const float* __restrict__ hA,
         const u64* __restrict__ bm, float* __restrict__ ep) {
  extern __shared__ float smem[];
  float* haj = smem;                 // [128][33]
  float* hj  = smem + 128 * 33;
  float* hak = smem + 2 * 128 * 33;
  float* hk  = smem + 3 * 128 * 33;

  int pid = blockIdx.x;              // 0..35
  int b = blockIdx.y;
  int Jt = 0;
  while (pid >= 8 - Jt) { pid -= (8 - Jt); Jt++; }
  int Kt = Jt + pid;

  int t = threadIdx.x;
  int tj = t >> 4;                   // 0..15
  int tk = t & 15;                   // 0..15
  const float* hb  = h  + (size_t)b * NN * DD;
  const float* hAb = hA + (size_t)b * NN * DD;

  float acc[8][8];
#pragma unroll
  for (int i = 0; i < 8; i++)
#pragma unroll
    for (int j = 0; j < 8; j++) acc[i][j] = 0.f;

  for (int kc = 0; kc < 128; kc += EB_BK) {
#pragma unroll
    for (int i = 0; i < 4; ++i) {
      int e = t + i * 256;
      int r = e >> 3, kq = e & 7;
      float4 v;
      v = *(const float4*)(hAb + (size_t)(Jt * 128 + r) * DD + kc + kq * 4);
      haj[r * 33 + kq * 4 + 0] = v.x; haj[r * 33 + kq * 4 + 1] = v.y;
      haj[r * 33 + kq * 4 + 2] = v.z; haj[r * 33 + kq * 4 + 3] = v.w;
      v = *(const float4*)(hb + (size_t)(Jt * 128 + r) * DD + kc + kq * 4);
      hj[r * 33 + kq * 4 + 0] = v.x; hj[r * 33 + kq * 4 + 1] = v.y;
      hj[r * 33 + kq * 4 + 2] = v.z; hj[r * 33 + kq * 4 + 3] = v.w;
      v = *(const float4*)(hAb + (size_t)(Kt * 128 + r) * DD + kc + kq * 4);
      hak[r * 33 + kq * 4 + 0] = v.x; hak[r * 33 + kq * 4 + 1] = v.y;
      hak[r * 33 + kq * 4 + 2] = v.z; hak[r * 33 + kq * 4 + 3] = v.w;
      v = *(const float4*)(hb + (size_t)(Kt * 128 + r) * DD + kc + kq * 4);
      hk[r * 33 + kq * 4 + 0] = v.x; hk[r * 33 + kq * 4 + 1] = v.y;
      hk[r * 33 + kq * 4 + 2] = v.z; hk[r * 33 + kq * 4 + 3] = v.w;
    }
    __syncthreads();
#pragma unroll
    for (int kk = 0; kk < EB_BK; ++kk) {
      float aJ[8], bK[8], aK[8], bJ[8];
#pragma unroll
      for (int i = 0; i < 8; i++) { aJ[i] = haj[(tj + 16 * i) * 33 + kk]; bJ[i] = hj[(tj + 16 * i) * 33 + kk]; }
#pragma unroll
      for (int j = 0; j < 8; j++) { bK[j] = hk[(tk + 16 * j) * 33 + kk]; aK[j] = hak[(tk + 16 * j) * 33 + kk]; }
#pragma unroll
      for (int i = 0; i < 8; i++)
#pragma unroll
        for (int j = 0; j < 8; j++)
          acc[i][j] = fmaf(aJ[i], bK[j], fmaf(aK[j], bJ[i], acc[i][j]));
    }
    __syncthreads();
  }

  // masked write: straight tile + mirror tile
#pragma unroll
  for (int i = 0; i < 8; i++) {
    int jr = Jt * 128 + tj + 16 * i;                    // row within batch
    u64 w0 = bm[((size_t)b * NN + jr) * 16 + 2 * Kt];
    u64 w1 = bm[((size_t)b * NN + jr) * 16 + 2 * Kt + 1];
#pragma unroll
    for (int j = 0; j < 8; j++) {
      int kc2 = tk + 16 * j;                            // 0..127
      int kcg = Kt * 128 + kc2;
      u64 w = (kc2 < 64) ? w0 : w1;
      int bit = (int)((w >> (kc2 & 63)) & 1ull);
      float v = bit ? acc[i][j] : 0.f;
      ep[((size_t)b * NN + jr) * NN + kcg] = v;
      ep[((size_t)b * NN + kcg) * NN + jr] = v;
    }
  }
}

// ---------------- column softmax stats (== row stats, e' symmetric) ----------------
__global__ void k_stats(const float* __restrict__ ep,
                        float* __restrict__ mrow, float* __restrict__ rden) {
  int row = blockIdx.x * 4 + (threadIdx.x >> 6);
  int l = threadIdx.x & 63;
  const float* er = ep + (size_t)row * NN;
  float v[16];
  float mx = -INFINITY;
#pragma unroll
  for (int r = 0; r < 16; r++) { v[r] = er[r * 64 + l]; mx = fmaxf(mx, v[r]); }
#pragma unroll
  for (int s = 1; s < 64; s <<= 1) mx = fmaxf(mx, __shfl_xor(mx, s, 64));
  float sum = 0.f;
#pragma unroll
  for (int r = 0; r < 16; r++) sum += __expf(v[r] - mx);
#pragma unroll
  for (int s = 1; s < 64; s <<= 1) sum += __shfl_xor(sum, s, 64);
  if (l == 0) { mrow[row] = mx; rden[row] = 1.0f / sum; }
}

// ---------------- build sparse normalized att lists (k-ascending) ----------------
__global__ void k_att(const float* __restrict__ ep, const u64* __restrict__ bm,
                      const float* __restrict__ mrow, const float* __restrict__ rden,
                      float* __restrict__ attv, u16* __restrict__ idx) {
  int row = blockIdx.x * 4 + (threadIdx.x >> 6);
  int l = threadIdx.x & 63;
  int bbase = row & ~(NN - 1);
  const float* er = ep + (size_t)row * NN;
  float* av = attv + (size_t)row * MAXDEG;
  u16* ir = idx + (size_t)row * MAXDEG;
  int base = 0;
  for (int r = 0; r < 16; r++) {
    u64 w = bm[row * 16 + r];
    int k = r * 64 + l;
    float v = er[k];
    if ((w >> l) & 1ull) {
      float a = __expf(v - mrow[bbase + k]) * rden[bbase + k];
      int pos = base + __popcll(w & ((1ull << l) - 1ull));
      if (pos < MAXDEG) { av[pos] = a; ir[pos] = (u16)k; }
    }
    base += __popcll(w);
  }
}

// ---------------- sparse az = relu(att @ z), 32-col tile in LDS ----------------
__global__ __launch_bounds__(256, 1)
void k_az(const float* __restrict__ z, const float* __restrict__ attv,
          const u16* __restrict__ idx, const u32* __restrict__ deg,
          float* __restrict__ az) {
  extern __shared__ float zl[];      // [1024][36] padded
  int b = blockIdx.x, kt = blockIdx.y, rc = blockIdx.z;
  int c0 = kt * 32;
  int t = threadIdx.x;
  const float* zb = z + (size_t)b * NN * DD;
#pragma unroll 8
  for (int i = 0; i < 32; i++) {
    int e = t + i * 256;
    int q = e >> 3, cq = e & 7;
    float4 v = *(const float4*)(zb + (size_t)q * DD + c0 + cq * 4);
    *(float4*)(zl + q * 36 + cq * 4) = v;
  }
  __syncthreads();

  int grow = b * NN + rc * 256 + t;
  int dgi = (int)deg[grow]; if (dgi > MAXDEG) dgi = MAXDEG;
  const u16* ir = idx + (size_t)grow * MAXDEG;
  const float* ar = attv + (size_t)grow * MAXDEG;

  float acc[32];
#pragma unroll
  for (int c = 0; c < 32; c++) acc[c] = 0.f;

  int s = 0;
  ushort4 q4 = {0, 0, 0, 0};
  float4 a4 = {0.f, 0.f, 0.f, 0.f};
  if (s + 4 <= dgi) { q4 = *(const ushort4*)(ir); a4 = *(const float4*)(ar); }
  for (; s + 4 <= dgi; s += 4) {
    ushort4 cq = q4; float4 ca = a4;
    if (s + 8 <= dgi) { q4 = *(const ushort4*)(ir + s + 4); a4 = *(const float4*)(ar + s + 4); }
    const unsigned short qq[4] = {cq.x, cq.y, cq.z, cq.w};
    const float aa[4] = {ca.x, ca.y, ca.z, ca.w};
#pragma unroll
    for (int e = 0; e < 4; e++) {
      const float* zr = zl + (int)qq[e] * 36;
      float a = aa[e];
#pragma unroll
      for (int cc = 0; cc < 8; cc++) {
        float4 zv = *(const float4*)(zr + cc * 4);
        acc[cc * 4 + 0] = fmaf(a, zv.x, acc[cc * 4 + 0]);
        acc[cc * 4 + 1] = fmaf(a, zv.y, acc[cc * 4 + 1]);
        acc[cc * 4 + 2] = fmaf(a, zv.z, acc[cc * 4 + 2]);
        acc[cc * 4 + 3] = fmaf(a, zv.w, acc[cc * 4 + 3]);
      }
    }
  }
  for (; s < dgi; s++) {
    int q = ir[s];
    float a = ar[s];
    const float* zr = zl + q * 36;
#pragma unroll
    for (int cc = 0; cc < 8; cc++) {
      float4 zv = *(const float4*)(zr + cc * 4);
      acc[cc * 4 + 0] = fmaf(a, zv.x, acc[cc * 4 + 0]);
      acc[cc * 4 + 1] = fmaf(a, zv.y, acc[cc * 4 + 1]);
      acc[cc * 4 + 2] = fmaf(a, zv.z, acc[cc * 4 + 2]);
      acc[cc * 4 + 3] = fmaf(a, zv.w, acc[cc * 4 + 3]);
    }
  }

  float* ao = az + (size_t)grow * DD + c0;
#pragma unroll
  for (int c = 0; c < 32; c += 4) {
    float4 v;
    v.x = fmaxf(acc[c + 0], 0.f); v.y = fmaxf(acc[c + 1], 0.f);
    v.z = fmaxf(acc[c + 2], 0.f); v.w = fmaxf(acc[c + 3], 0.f);
    *(float4*)(ao + c) = v;
  }
}

// ---------------- gate + mix: z = c*x + (1-c)*az ----------------
__global__ void k_gate(const float* __restrict__ x, const float* __restrict__ az,
                       const float* __restrict__ gw, const float* __restrict__ gb,
                       float* __restrict__ zo) {
  int row = blockIdx.x * 4 + (threadIdx.x >> 6);
  int l = threadIdx.x & 63;
  const float* xr = x + (size_t)row * DD;
  const float* ar = az + (size_t)row * DD;
  float x0 = xr[l], x1 = xr[l + 64];
  float a0 = ar[l], a1 = ar[l + 64];
  float p = gw[l] * x0 + gw[l + 64] * x1 + gw[128 + l] * a0 + gw[192 + l] * a1;
#pragma unroll
  for (int s = 1; s < 64; s <<= 1) p += __shfl_xor(p, s, 64);
  float cf = 1.0f / (1.0f + __expf(-(p + gb[0])));
  zo[(size_t)row * DD + l] = cf * x0 + (1.f - cf) * a0;
  zo[(size_t)row * DD + l + 64] = cf * x1 + (1.f - cf) * a1;
}

extern "C" void kernel_launch(void* const* d_in, const int* in_sizes, int n_in,
                              void* d_out, int out_size, void* d_ws, size_t ws_size,
                              hipStream_t stream) {
  const float* x   = (const float*)d_in[0];
  const float* adj = (const float*)d_in[1];
  const float* W_w = (const float*)d_in[2];
  const float* W_b = (const float*)d_in[3];
  const float* A   = (const float*)d_in[4];
  const float* gw  = (const float*)d_in[5];
  const float* gb  = (const float*)d_in[6];
  float* out = (float*)d_out;

  char* p = (char*)d_ws;
  auto alloc = [&](size_t bytes) -> void* {
    void* r = (void*)p;
    p += (bytes + 255) & ~(size_t)255;
    return r;
  };
  float* h    = (float*)alloc((size_t)RR * DD * 4);        // also z buffer
  float* hA   = (float*)alloc((size_t)RR * DD * 4);        // also az buffer
  float* ep   = (float*)alloc((size_t)RR * NN * 4);        // dense masked e'
  u64*   bm   = (u64*)alloc((size_t)RR * 16 * 8);
  u32*   deg  = (u32*)alloc((size_t)RR * 4);
  float* mrow = (float*)alloc((size_t)RR * 4);
  float* rden = (float*)alloc((size_t)RR * 4);
  float* attv = (float*)alloc((size_t)RR * MAXDEG * 4);
  u16*   idx  = (u16*)alloc((size_t)RR * MAXDEG * 2);
  float* At   = (float*)alloc((size_t)DD * DD * 4);

  k_compact<<<RR, 64, 0, stream>>>(adj, bm, deg);
  k_transpose<<<64, 256, 0, stream>>>(A, At);
  k_gemm_bt<<<RR / 64, 256, 0, stream>>>(x, W_w, W_b, h);     // h = x W^T + b
  k_gemm_bt<<<RR / 64, 256, 0, stream>>>(h, At, nullptr, hA); // hA = h A
  size_t e_lds = (size_t)4 * 128 * 33 * sizeof(float);
  k_e<<<dim3(36, 16), 256, e_lds, stream>>>(h, hA, bm, ep);
  k_stats<<<RR / 4, 256, 0, stream>>>(ep, mrow, rden);
  k_att<<<RR / 4, 256, 0, stream>>>(ep, bm, mrow, rden, attv, idx);

  size_t az_lds = (size_t)1024 * 36 * sizeof(float);
  for (int hop = 0; hop < NHOP; ++hop) {
    k_az<<<dim3(16, 4, 4), 256, az_lds, stream>>>(h, attv, idx, deg, hA);
    float* zo = (hop == NHOP - 1) ? out : h;
    k_gate<<<RR / 4, 256, 0, stream>>>(x, hA, gw, gb, zo);
  }
}

// Round 3
// 490.888 us; speedup vs baseline: 1.0224x; 1.0224x over previous
//
#include <hip/hip_runtime.h>
#include <cstdint>
#include <cstddef>

#define BB 16
#define NN 1024
#define DD 128
#define RR (BB*NN)
#define NHOP 4
#define KSPLIT 4

typedef unsigned long long u64;
typedef unsigned short u16;
typedef unsigned int u32;
typedef __attribute__((ext_vector_type(8))) short bf16x8;
typedef __attribute__((ext_vector_type(4))) float f32x4;

__device__ __forceinline__ u16 f2bf(float f) {
  union { float f; u32 u; } c; c.f = f;
  u32 r = c.u + 0x7FFFu + ((c.u >> 16) & 1u);
  return (u16)(r >> 16);
}
__device__ __forceinline__ float bf2f(u16 h) {
  union { u32 u; float f; } c; c.u = ((u32)h) << 16;
  return c.f;
}

// ---------------- K0: adjacency row -> bitmask ----------------
__global__ void k_compact(const float* __restrict__ adj, u64* __restrict__ bm) {
  int row = blockIdx.x;
  int l = threadIdx.x;
  const float* arow = adj + (size_t)row * NN;
  for (int r = 0; r < 16; ++r) {
    float v = arow[r * 64 + l];
    u64 m = __ballot(v > 0.0f);
    if (l == 0) bm[row * 16 + r] = m;
  }
}

// ---------------- transpose A ----------------
__global__ void k_transpose(const float* __restrict__ A, float* __restrict__ At) {
  int e = blockIdx.x * 256 + threadIdx.x;
  int r = e >> 7, c = e & 127;
  At[c * 128 + r] = A[r * 128 + c];
}

// ---------------- C[M x 128] = A[M x 128] * B^T (+bias), B row-major [out][k] ----------------
#define GB_BK 64
__global__ __launch_bounds__(256, 3)
void k_gemm_bt(const float* __restrict__ Am, const float* __restrict__ Bm,
               const float* __restrict__ bias, float* __restrict__ Cm) {
  __shared__ float a_lds[64][GB_BK + 1];
  __shared__ float b_lds[128][GB_BK + 1];
  int t = threadIdx.x;
  int tj = t >> 5, tk = t & 31;
  int rowbase = blockIdx.x * 64;
  float acc[8][4];
#pragma unroll
  for (int i = 0; i < 8; i++)
#pragma unroll
    for (int j = 0; j < 4; j++) acc[i][j] = 0.f;

  for (int kc = 0; kc < 128; kc += GB_BK) {
#pragma unroll
    for (int i = 0; i < 4; ++i) {
      int e = t + i * 256;
      int r = e >> 4, kq = e & 15;
      float4 v = *(const float4*)(Am + (size_t)(rowbase + r) * DD + kc + kq * 4);
      a_lds[r][kq * 4 + 0] = v.x; a_lds[r][kq * 4 + 1] = v.y;
      a_lds[r][kq * 4 + 2] = v.z; a_lds[r][kq * 4 + 3] = v.w;
    }
#pragma unroll
    for (int i = 0; i < 8; ++i) {
      int e = t + i * 256;
      int r = e >> 4, kq = e & 15;
      float4 v = *(const float4*)(Bm + (size_t)r * DD + kc + kq * 4);
      b_lds[r][kq * 4 + 0] = v.x; b_lds[r][kq * 4 + 1] = v.y;
      b_lds[r][kq * 4 + 2] = v.z; b_lds[r][kq * 4 + 3] = v.w;
    }
    __syncthreads();
#pragma unroll
    for (int kk = 0; kk < GB_BK; ++kk) {
      float av[8], bv[4];
#pragma unroll
      for (int i = 0; i < 8; i++) av[i] = a_lds[tj + 8 * i][kk];
#pragma unroll
      for (int j = 0; j < 4; j++) bv[j] = b_lds[tk + 32 * j][kk];
#pragma unroll
      for (int i = 0; i < 8; i++)
#pragma unroll
        for (int j = 0; j < 4; j++)
          acc[i][j] = fmaf(av[i], bv[j], acc[i][j]);
    }
    __syncthreads();
  }
#pragma unroll
  for (int i = 0; i < 8; i++) {
    int gr = rowbase + tj + 8 * i;
#pragma unroll
    for (int j = 0; j < 4; j++) {
      int c = tk + 32 * j;
      float v = acc[i][j];
      if (bias) v += bias[c];
      Cm[(size_t)gr * DD + c] = v;
    }
  }
}

// ---------------- e' kernel: symmetric bilinear masked scores ----------------
// BK=16, stride 20 -> 40.9KB LDS -> 3 blocks/CU -> 576 blocks in ONE round.
#define EB_BK 16
#define EP 20
__global__ __launch_bounds__(256, 3)
void k_e(const float* __restrict__ h, const float* __restrict__ hA,
         const u64* __restrict__ bm, float* __restrict__ ep) {
  __shared__ float smem[4 * 128 * EP];
  float* haj = smem;
  float* hj  = smem + 128 * EP;
  float* hak = smem + 2 * 128 * EP;
  float* hk  = smem + 3 * 128 * EP;

  int pid = blockIdx.x;       // 0..35
  int b = blockIdx.y;
  int Jt = 0;
  while (pid >= 8 - Jt) { pid -= (8 - Jt); Jt++; }
  int Kt = Jt + pid;

  int t = threadIdx.x;
  int tj = t >> 4, tk = t & 15;
  const float* hb  = h  + (size_t)b * NN * DD;
  const float* hAb = hA + (size_t)b * NN * DD;
  const float* srcs[4] = { hAb + (size_t)Jt * 128 * DD, hb + (size_t)Jt * 128 * DD,
                           hAb + (size_t)Kt * 128 * DD, hb + (size_t)Kt * 128 * DD };

  float acc[8][8];
#pragma unroll
  for (int i = 0; i < 8; i++)
#pragma unroll
    for (int j = 0; j < 8; j++) acc[i][j] = 0.f;

  for (int kc = 0; kc < 128; kc += EB_BK) {
#pragma unroll
    for (int arr = 0; arr < 4; ++arr) {
      const float* sp = srcs[arr];
      float* dp = smem + arr * 128 * EP;
#pragma unroll
      for (int i = 0; i < 2; ++i) {
        int e = t + i * 256;
        int r = e >> 2, kq = e & 3;
        float4 v = *(const float4*)(sp + (size_t)r * DD + kc + kq * 4);
        *(float4*)(dp + r * EP + kq * 4) = v;
      }
    }
    __syncthreads();
#pragma unroll
    for (int kk = 0; kk < EB_BK; kk += 2) {
      float2 aJ[8], bJ[8], aK[8], bK[8];
#pragma unroll
      for (int i = 0; i < 8; ++i) {
        aJ[i] = *(const float2*)(haj + (tj + 16 * i) * EP + kk);
        bJ[i] = *(const float2*)(hj  + (tj + 16 * i) * EP + kk);
        aK[i] = *(const float2*)(hak + (tk + 16 * i) * EP + kk);
        bK[i] = *(const float2*)(hk  + (tk + 16 * i) * EP + kk);
      }
#pragma unroll
      for (int i = 0; i < 8; i++)
#pragma unroll
        for (int j = 0; j < 8; j++) {
          acc[i][j] = fmaf(aJ[i].x, bK[j].x, acc[i][j]);
          acc[i][j] = fmaf(aJ[i].y, bK[j].y, acc[i][j]);
          acc[i][j] = fmaf(aK[j].x, bJ[i].x, acc[i][j]);
          acc[i][j] = fmaf(aK[j].y, bJ[i].y, acc[i][j]);
        }
    }
    __syncthreads();
  }

#pragma unroll
  for (int i = 0; i < 8; i++) {
    int jr = Jt * 128 + tj + 16 * i;
    u64 w0 = bm[((size_t)b * NN + jr) * 16 + 2 * Kt];
    u64 w1 = bm[((size_t)b * NN + jr) * 16 + 2 * Kt + 1];
#pragma unroll
    for (int j = 0; j < 8; j++) {
      int kc2 = tk + 16 * j;
      int kcg = Kt * 128 + kc2;
      u64 w = (kc2 < 64) ? w0 : w1;
      int bit = (int)((w >> (kc2 & 63)) & 1ull);
      float v = bit ? acc[i][j] : 0.f;
      ep[((size_t)b * NN + jr) * NN + kcg] = v;
      ep[((size_t)b * NN + kcg) * NN + jr] = v;
    }
  }
}

// ---------------- per-row (== per-column, symmetric) softmax stats ----------------
__global__ void k_stats(const float* __restrict__ ep,
                        float* __restrict__ mrow, float* __restrict__ rden) {
  int row = blockIdx.x * 4 + (threadIdx.x >> 6);
  int l = threadIdx.x & 63;
  const float* er = ep + (size_t)row * NN;
  float v[16];
  float mx = -INFINITY;
#pragma unroll
  for (int r = 0; r < 16; r++) { v[r] = er[r * 64 + l]; mx = fmaxf(mx, v[r]); }
#pragma unroll
  for (int s = 1; s < 64; s <<= 1) mx = fmaxf(mx, __shfl_xor(mx, s, 64));
  float sum = 0.f;
#pragma unroll
  for (int r = 0; r < 16; r++) sum += __expf(v[r] - mx);
#pragma unroll
  for (int s = 1; s < 64; s <<= 1) sum += __shfl_xor(sum, s, 64);
  if (l == 0) { mrow[row] = mx; rden[row] = 1.0f / sum; }
}

// ---------------- dense att build: att_hi/att_lo bf16 ----------------
__global__ __launch_bounds__(256, 2)
void k_att_dense(const float* __restrict__ ep, const u64* __restrict__ bm,
                 const float* __restrict__ mrow, const float* __restrict__ rden,
                 u16* __restrict__ ahi, u16* __restrict__ alo) {
  __shared__ float ml[NN];
  __shared__ float rl[NN];
  int g = blockIdx.x;              // 0..255
  int b = g >> 4;
  int t = threadIdx.x;
  int w = t >> 6, l = t & 63;
#pragma unroll
  for (int i = 0; i < 4; ++i) {
    ml[t + i * 256] = mrow[(size_t)b * NN + t + i * 256];
    rl[t + i * 256] = rden[(size_t)b * NN + t + i * 256];
  }
  __syncthreads();

  for (int rr = 0; rr < 16; ++rr) {
    int row = g * 64 + rr * 4 + w;                  // global row
    const float* er = ep + (size_t)row * NN;
    u16* oh = ahi + (size_t)row * NN;
    u16* ol = alo + (size_t)row * NN;
    const u64* bw = bm + (size_t)row * 16;
#pragma unroll
    for (int pass = 0; pass < 4; ++pass) {
      int c = pass * 256 + l * 4;
      float4 e4 = *(const float4*)(er + c);
      u64 wbits = bw[c >> 6];
      float av[4];
#pragma unroll
      for (int j = 0; j < 4; ++j) {
        int k = c + j;
        float e = (j == 0) ? e4.x : (j == 1) ? e4.y : (j == 2) ? e4.z : e4.w;
        int bit = (int)((wbits >> (k & 63)) & 1ull);
        av[j] = bit ? __expf(e - ml[k]) * rl[k] : 0.f;
      }
      ushort4 vh, vl;
      vh.x = f2bf(av[0]); vl.x = f2bf(av[0] - bf2f(vh.x));
      vh.y = f2bf(av[1]); vl.y = f2bf(av[1] - bf2f(vh.y));
      vh.z = f2bf(av[2]); vl.z = f2bf(av[2] - bf2f(vh.z));
      vh.w = f2bf(av[3]); vl.w = f2bf(av[3] - bf2f(vh.w));
      *(ushort4*)(oh + c) = vh;
      *(ushort4*)(ol + c) = vl;
    }
  }
}

// ---------------- h -> hT hi/lo bf16 (transposed, B-operand prep for hop 0) ----------------
#define TP 133
__global__ __launch_bounds__(256, 2)
void k_prep(const float* __restrict__ h, u16* __restrict__ zth, u16* __restrict__ ztl) {
  __shared__ float tile[64 * TP];
  int g = blockIdx.x;              // 0..255 : rows [g*64, +64)
  int b = g >> 4;
  int rbb = (g & 15) * 64;
  int t = threadIdx.x;
#pragma unroll
  for (int i = 0; i < 8; ++i) {
    int e = t + i * 256;
    int r = e >> 5, cq = e & 31;
    float4 v = *(const float4*)(h + (size_t)(g * 64 + r) * DD + cq * 4);
    tile[r * TP + cq * 4 + 0] = v.x; tile[r * TP + cq * 4 + 1] = v.y;
    tile[r * TP + cq * 4 + 2] = v.z; tile[r * TP + cq * 4 + 3] = v.w;
  }
  __syncthreads();
#pragma unroll
  for (int it = 0; it < 32; ++it) {
    int c = it * 4 + (t >> 6);
    int row = t & 63;
    float v = tile[row * TP + c];
    u16 hi = f2bf(v);
    u16 lo = f2bf(v - bf2f(hi));
    size_t o = (size_t)b * DD * NN + (size_t)c * NN + rbb + row;
    zth[o] = hi; ztl[o] = lo;
  }
}

// ---------------- hop: az_partial = att @ z via bf16 hi/lo MFMA, split-K=4 ----------------
// grid (rt=8, ks=4, b=16) = 512 blocks = 2/CU. LDS 64KB.
__global__ __launch_bounds__(256, 1)
void k_az_mfma(const u16* __restrict__ ahi, const u16* __restrict__ alo,
               const u16* __restrict__ zth, const u16* __restrict__ ztl,
               float* __restrict__ azp) {
  __shared__ u16 lds[4][128 * 64];
  int rt = blockIdx.x;
  int ks = blockIdx.y;
  int b  = blockIdx.z;
  int t = threadIdx.x;
  int w = t >> 6, l = t & 63;
  int wm = w >> 1, wn = w & 1;
  int k0 = ks * (NN / KSPLIT);

  const u16* srcs[4] = {
    ahi + ((size_t)b * NN + rt * 128) * NN + k0,
    alo + ((size_t)b * NN + rt * 128) * NN + k0,
    zth + (size_t)b * DD * NN + k0,
    ztl + (size_t)b * DD * NN + k0
  };

  f32x4 acc[4][4];
#pragma unroll
  for (int i = 0; i < 4; i++)
#pragma unroll
    for (int j = 0; j < 4; j++) acc[i][j] = (f32x4)(0.f);

  for (int kb = 0; kb < NN / KSPLIT; kb += 64) {
    // stage: 4 arrays x [128][64] bf16; source k-chunk pre-swizzled (rule #21)
#pragma unroll
    for (int arr = 0; arr < 4; ++arr) {
      const u16* sp = srcs[arr] + kb;
#pragma unroll
      for (int c = 0; c < 4; ++c) {
        int chunk = w * 4 + c;                   // wave-uniform
        int row = chunk * 8 + (l >> 3);
        int slot = l & 7;
        const u16* gp = sp + (size_t)row * NN + ((slot ^ (row & 7)) << 3);
        u16* lp = &lds[arr][chunk * 512];        // HW adds lane*16B
        __builtin_amdgcn_global_load_lds(
            (const __attribute__((address_space(1))) void*)gp,
            (__attribute__((address_space(3))) void*)lp, 16, 0, 0);
      }
    }
    __syncthreads();   // compiler drains vmcnt before s_barrier

#pragma unroll
    for (int ks2 = 0; ks2 < 2; ++ks2) {
      int s = ks2 * 4 + (l >> 4);
      bf16x8 ah[4], al4[4], bh[4], bl4[4];
#pragma unroll
      for (int mi = 0; mi < 4; ++mi) {
        int m = wm * 64 + mi * 16 + (l & 15);
        int off = m * 64 + ((s ^ (m & 7)) << 3);
        ah[mi]  = *(const bf16x8*)&lds[0][off];
        al4[mi] = *(const bf16x8*)&lds[1][off];
      }
#pragma unroll
      for (int ni = 0; ni < 4; ++ni) {
        int n = wn * 64 + ni * 16 + (l & 15);
        int off = n * 64 + ((s ^ (n & 7)) << 3);
        bh[ni]  = *(const bf16x8*)&lds[2][off];
        bl4[ni] = *(const bf16x8*)&lds[3][off];
      }
#pragma unroll
      for (int mi = 0; mi < 4; ++mi)
#pragma unroll
        for (int ni = 0; ni < 4; ++ni) {
          acc[mi][ni] = __builtin_amdgcn_mfma_f32_16x16x32_bf16(ah[mi],  bh[ni],  acc[mi][ni], 0, 0, 0);
          acc[mi][ni] = __builtin_amdgcn_mfma_f32_16x16x32_bf16(ah[mi],  bl4[ni], acc[mi][ni], 0, 0, 0);
          acc[mi][ni] = __builtin_amdgcn_mfma_f32_16x16x32_bf16(al4[mi], bh[ni],  acc[mi][ni], 0, 0, 0);
        }
    }
    __syncthreads();
  }

  // C/D layout: col = lane&15, row = (lane>>4)*4 + reg  [m89-verified]
  float* dst = azp + ((size_t)ks * RR + (size_t)b * NN + rt * 128) * DD;
#pragma unroll
  for (int mi = 0; mi < 4; ++mi)
#pragma unroll
    for (int ni = 0; ni < 4; ++ni) {
      int row = wm * 64 + mi * 16 + ((l >> 4) << 2);
      int col = wn * 64 + ni * 16 + (l & 15);
#pragma unroll
      for (int r = 0; r < 4; ++r)
        dst[(size_t)(row + r) * DD + col] = acc[mi][ni][r];
    }
}

// ---------------- gate: a=relu(sum partials); coeff=sigmoid(gw.[x,a]+gb); z=c*x+(1-c)*a ----------------
__global__ __launch_bounds__(256, 2)
void k_gate2(const float* __restrict__ x, const float* __restrict__ azp,
             const float* __restrict__ gw, const float* __restrict__ gb, int last,
             u16* __restrict__ zth, u16* __restrict__ ztl, float* __restrict__ out) {
  __shared__ float axl[64 * TP];
  __shared__ float coeff[64];
  int g = blockIdx.x;              // rows [g*64, +64)
  int b = g >> 4;
  int rbb = (g & 15) * 64;
  int t = threadIdx.x;

#pragma unroll
  for (int i = 0; i < 8; ++i) {
    int e = t + i * 256;
    int r = e >> 5, cq = e & 31;
    size_t o = (size_t)(g * 64 + r) * DD + cq * 4;
    float4 v0 = *(const float4*)(azp + o);
    float4 v1 = *(const float4*)(azp + (size_t)RR * DD + o);
    float4 v2 = *(const float4*)(azp + 2 * (size_t)RR * DD + o);
    float4 v3 = *(const float4*)(azp + 3 * (size_t)RR * DD + o);
    axl[r * TP + cq * 4 + 0] = fmaxf(v0.x + v1.x + v2.x + v3.x, 0.f);
    axl[r * TP + cq * 4 + 1] = fmaxf(v0.y + v1.y + v2.y + v3.y, 0.f);
    axl[r * TP + cq * 4 + 2] = fmaxf(v0.z + v1.z + v2.z + v3.z, 0.f);
    axl[r * TP + cq * 4 + 3] = fmaxf(v0.w + v1.w + v2.w + v3.w, 0.f);
  }
  __syncthreads();

  {
    int rl = t >> 2, part = t & 3;
    const float* xr = x + (size_t)(g * 64 + rl) * DD;
    float s = 0.f;
#pragma unroll
    for (int i = 0; i < 32; ++i) {
      int c = part * 32 + i;
      s += gw[c] * xr[c] + gw[128 + c] * axl[rl * TP + c];
    }
    s += __shfl_xor(s, 1, 64);
    s += __shfl_xor(s, 2, 64);
    if (part == 0) coeff[rl] = 1.0f / (1.0f + __expf(-(s + gb[0])));
  }
  __syncthreads();

  // mix in-place (coalesced x reads), z = cf*x + (1-cf)*az
#pragma unroll
  for (int i = 0; i < 8; ++i) {
    int e = t + i * 256;
    int r = e >> 5, cq = e & 31;
    float cf = coeff[r];
    float4 xv = *(const float4*)(x + (size_t)(g * 64 + r) * DD + cq * 4);
    axl[r * TP + cq * 4 + 0] = cf * xv.x + (1.f - cf) * axl[r * TP + cq * 4 + 0];
    axl[r * TP + cq * 4 + 1] = cf * xv.y + (1.f - cf) * axl[r * TP + cq * 4 + 1];
    axl[r * TP + cq * 4 + 2] = cf * xv.z + (1.f - cf) * axl[r * TP + cq * 4 + 2];
    axl[r * TP + cq * 4 + 3] = cf * xv.w + (1.f - cf) * axl[r * TP + cq * 4 + 3];
  }
  __syncthreads();

  if (last) {
#pragma unroll
    for (int i = 0; i < 8; ++i) {
      int e = t + i * 256;
      int r = e >> 5, cq = e & 31;
      float4 v;
      v.x = axl[r * TP + cq * 4 + 0]; v.y = axl[r * TP + cq * 4 + 1];
      v.z = axl[r * TP + cq * 4 + 2]; v.w = axl[r * TP + cq * 4 + 3];
      *(float4*)(out + (size_t)(g * 64 + r) * DD + cq * 4) = v;
    }
  } else {
#pragma unroll
    for (int it = 0; it < 32; ++it) {
      int c = it * 4 + (t >> 6);
      int row = t & 63;
      float v = axl[row * TP + c];
      u16 hi = f2bf(v);
      u16 lo = f2bf(v - bf2f(hi));
      size_t o = (size_t)b * DD * NN + (size_t)c * NN + rbb + row;
      zth[o] = hi; ztl[o] = lo;
    }
  }
}

extern "C" void kernel_launch(void* const* d_in, const int* in_sizes, int n_in,
                              void* d_out, int out_size, void* d_ws, size_t ws_size,
                              hipStream_t stream) {
  const float* x   = (const float*)d_in[0];
  const float* adj = (const float*)d_in[1];
  const float* W_w = (const float*)d_in[2];
  const float* W_b = (const float*)d_in[3];
  const float* A   = (const float*)d_in[4];
  const float* gw  = (const float*)d_in[5];
  const float* gb  = (const float*)d_in[6];
  float* out = (float*)d_out;

  char* p = (char*)d_ws;
  auto alloc = [&](size_t bytes) -> void* {
    void* r = (void*)p;
    p += (bytes + 255) & ~(size_t)255;
    return r;
  };
  float* h    = (float*)alloc((size_t)RR * DD * 4);        // 8.4 MB
  float* hA   = (float*)alloc((size_t)RR * DD * 4);        // 8.4 MB
  float* ep   = (float*)alloc((size_t)RR * NN * 4);        // 67 MB
  u64*   bm   = (u64*)alloc((size_t)RR * 16 * 8);          // 2.1 MB
  float* mrow = (float*)alloc((size_t)RR * 4);
  float* rden = (float*)alloc((size_t)RR * 4);
  u16*   ahi  = (u16*)alloc((size_t)RR * NN * 2);          // 33.5 MB
  u16*   alo  = (u16*)alloc((size_t)RR * NN * 2);          // 33.5 MB
  float* At   = (float*)alloc((size_t)DD * DD * 4);

  // overlays into dead ep region (ep fully consumed after k_att_dense):
  // azp: KSPLIT partials 33.5 MB at +0; zth/ztl at +40/+48 MB (disjoint).
  float* azp = ep;
  u16* zth = (u16*)((char*)ep + ((size_t)40 << 20));
  u16* ztl = (u16*)((char*)ep + ((size_t)48 << 20));

  k_compact<<<RR, 64, 0, stream>>>(adj, bm);
  k_transpose<<<64, 256, 0, stream>>>(A, At);
  k_gemm_bt<<<RR / 64, 256, 0, stream>>>(x, W_w, W_b, h);     // h = x W^T + b
  k_gemm_bt<<<RR / 64, 256, 0, stream>>>(h, At, nullptr, hA); // hA = h A
  k_e<<<dim3(36, BB), 256, 0, stream>>>(h, hA, bm, ep);
  k_stats<<<RR / 4, 256, 0, stream>>>(ep, mrow, rden);
  k_att_dense<<<RR / 64, 256, 0, stream>>>(ep, bm, mrow, rden, ahi, alo);
  k_prep<<<RR / 64, 256, 0, stream>>>(h, zth, ztl);           // after ep is dead

  for (int hop = 0; hop < NHOP; ++hop) {
    k_az_mfma<<<dim3(8, KSPLIT, BB), 256, 0, stream>>>(ahi, alo, zth, ztl, azp);
    int last = (hop == NHOP - 1);
    k_gate2<<<RR / 64, 256, 0, stream>>>(x, azp, gw, gb, last, zth, ztl, out);
  }
}